// Round 9
// baseline (602.337 us; speedup 1.0000x reference)
//
#include <hip/hip_runtime.h>

#define N_VOX 100000
#define K3 125
#define CENTER_K 62
#define TVOX 128
#define NBLK 782            // ceil(100000/128)
#define CAP2 640            // per-tile entry cap (mean 388, sigma ~20)
#define EPSF 1e-5f

// ws float-word offsets
#define WIT 0               // W_img lane-order [125][8][32][4]  (c = q*32+t*4+e, l32 = q*16+o)
#define WPT 128000          // W_pts lane-order [125][4][32][4]  (c = q*16+t*4+e)
#define WVT 192000          // W_vis lane-order [125][4][32][4]
#define GCNT 256000         // per-tile counters [1024]
#define GLIST 257024        // unsorted entries [NBLK][CAP2]
#define KOFF  757504        // per-tile inclusive k-offsets [NBLK][128]
#define SLIST 857600        // k-sorted entries [NBLK][CAP2]
#define CAT   1358080       // cat [N_VOX][32]
// end = 4,558,080 words = 18.3 MB

#define DOT4(f_, g_) ((f_).x*(g_).x + (f_).y*(g_).y + (f_).z*(g_).z + (f_).w*(g_).w)

__global__ __launch_bounds__(256) void prep_transpose(
    const float* __restrict__ Wi, const float* __restrict__ Wp,
    const float* __restrict__ Wv, float* __restrict__ ws)
{
    int i = blockIdx.x * 256 + threadIdx.x;
    if (i < 125 * 64 * 16) {            // img: i = k*1024 + c*16 + o
        int k = i >> 10, r = i & 1023;
        int c = r >> 4, oo = r & 15;
        int qq = c >> 5, t = (c >> 2) & 7, e = c & 3;
        ws[WIT + k * 1024 + t * 128 + (qq * 16 + oo) * 4 + e] = Wi[i];
    }
    if (i < 125 * 32 * 16) {            // pts/vis: i = k*512 + c*16 + o
        int k = i >> 9, r = i & 511;
        int c = r >> 4, oo = r & 15;
        int qq = c >> 4, t = (c >> 2) & 3, e = c & 3;
        ws[WPT + k * 512 + t * 128 + (qq * 16 + oo) * 4 + e] = Wp[i];
        ws[WVT + k * 512 + t * 128 + (qq * 16 + oo) * 4 + e] = Wv[i];
    }
}

// single nbr pass -> per-destination-tile lists (center tap handled densely)
__global__ __launch_bounds__(256) void build(const int* __restrict__ nbr,
                                             float* __restrict__ ws)
{
    int* gcnt = (int*)(ws + GCNT);
    int* glist = (int*)(ws + GLIST);
    const int TOT4 = (N_VOX * K3) / 4;   // 3,125,000 exact
    const int4* n4 = (const int4*)nbr;
    for (int i4 = blockIdx.x * 256 + threadIdx.x; i4 < TOT4; i4 += gridDim.x * 256) {
        int4 v = n4[i4];
        int base = i4 * 4;
        int idxs[4] = {v.x, v.y, v.z, v.w};
        #pragma unroll
        for (int j = 0; j < 4; ++j) {
            int idx = idxs[j];
            int i = base + j;
            unsigned n = (unsigned)i / K3;
            int k = i - (int)n * K3;
            if (idx < N_VOX && k != CENTER_K) {
                int blk = n >> 7, ln = n & 127;
                int pos = atomicAdd(&gcnt[blk], 1);
                if (pos < CAP2)
                    glist[(size_t)blk * CAP2 + pos] = (k << 24) | (ln << 17) | idx;
            }
        }
    }
}

// img+pts conv: per-tile k-sort + center init + k-segment march with LDS accumulation
__global__ __launch_bounds__(256, 3) void convA(
    const float* __restrict__ fimg, const float* __restrict__ fpts,
    float* __restrict__ ws,
    const float* __restrict__ gi, const float* __restrict__ bi,
    const float* __restrict__ mi, const float* __restrict__ vi,
    const float* __restrict__ gp, const float* __restrict__ bp,
    const float* __restrict__ mp, const float* __restrict__ vp)
{
    __shared__ int s_kcnt[128];
    __shared__ int s_koff[128];
    __shared__ int s_list[CAP2];
    __shared__ float s_acc[TVOX][32];
    __shared__ int s_next;

    const int tid = threadIdx.x;
    const int lane = tid & 63, wv = tid >> 6;
    const int l32 = lane & 31, qp = (lane >> 4) & 1, o = lane & 15, s2 = lane >> 5;
    const int blk = blockIdx.x, gbase = blk * TVOX;
    const int vcount = min(TVOX, N_VOX - gbase);

    if (tid < 128) s_kcnt[tid] = 0;
    if (tid == 0) s_next = 0;
    __syncthreads();

    const int cnt = min(((const int*)(ws + GCNT))[blk], CAP2);
    const int* gl = (const int*)(ws + GLIST) + (size_t)blk * CAP2;

    for (int p = tid; p < cnt; p += 256)
        atomicAdd(&s_kcnt[((unsigned)gl[p]) >> 24], 1);
    __syncthreads();

    if (tid < 128) s_koff[tid] = (tid < K3) ? s_kcnt[tid] : 0;
    __syncthreads();
    for (int d = 1; d < 128; d <<= 1) {       // inclusive scan
        int v = 0;
        if (tid < 128 && tid >= d) v = s_koff[tid - d];
        __syncthreads();
        if (tid < 128) s_koff[tid] += v;
        __syncthreads();
    }
    if (tid < 128) s_kcnt[tid] = tid ? s_koff[tid - 1] : 0;   // cursors
    __syncthreads();

    for (int p = tid; p < cnt; p += 256) {
        int ent = gl[p];
        int pos = atomicAdd(&s_kcnt[((unsigned)ent) >> 24], 1);
        s_list[pos] = ent;
    }
    __syncthreads();

    {   // save sorted list + offsets for convB
        int tot = s_koff[K3 - 1];
        int* kfo = (int*)(ws + KOFF) + (size_t)blk * 128;
        int* slo = (int*)(ws + SLIST) + (size_t)blk * CAP2;
        if (tid < K3) kfo[tid] = s_koff[tid];
        for (int p = tid; p < tot; p += 256) slo[p] = s_list[p];
    }

    const float4* __restrict__ fi4 = (const float4*)fimg;
    const float4* __restrict__ fp4 = (const float4*)fpts;

    // center tap: init s_acc (2 voxels per wave-iter via s2 halves)
    {
        float4 wi[8], wp[4];
        const float4* WI = (const float4*)(ws + WIT + CENTER_K * 1024);
        const float4* WP = (const float4*)(ws + WPT + CENTER_K * 512);
        #pragma unroll
        for (int t = 0; t < 8; ++t) wi[t] = WI[t * 32 + l32];
        #pragma unroll
        for (int t = 0; t < 4; ++t) wp[t] = WP[t * 32 + l32];
        for (int i = 0; i < 16; ++i) {
            int ln = wv * 32 + i * 2 + s2;
            bool val = ln < vcount;
            int j = gbase + (val ? ln : 0);
            const float4* F = fi4 + (size_t)j * 16 + qp * 8;
            const float4* G = fp4 + (size_t)j * 8 + qp * 4;
            float aI = 0.f, aP = 0.f;
            #pragma unroll
            for (int t = 0; t < 8; ++t) aI += DOT4(F[t], wi[t]);
            #pragma unroll
            for (int t = 0; t < 4; ++t) aP += DOT4(G[t], wp[t]);
            aI += __shfl_xor(aI, 16);
            aP += __shfl_xor(aP, 16);
            if (val) s_acc[ln][qp * 16 + o] = qp ? aP : aI;
        }
    }
    __syncthreads();

    // k-segment march: W[k] in regs, 2 pair-chains per wave
    while (true) {
        int sseg;
        if (lane == 0) sseg = atomicAdd(&s_next, 1);
        sseg = __shfl(sseg, 0);
        if (sseg >= K3) break;
        int pbeg = sseg ? s_koff[sseg - 1] : 0;
        int pend = s_koff[sseg];
        if (pbeg >= pend) continue;
        float4 wi[8], wp[4];
        const float4* WI = (const float4*)(ws + WIT + sseg * 1024);
        const float4* WP = (const float4*)(ws + WPT + sseg * 512);
        #pragma unroll
        for (int t = 0; t < 8; ++t) wi[t] = WI[t * 32 + l32];
        #pragma unroll
        for (int t = 0; t < 4; ++t) wp[t] = WP[t * 32 + l32];
        for (int p = pbeg; p < pend; p += 2) {
            int pp = p + s2;
            bool val = pp < pend;
            int ent = s_list[val ? pp : p];
            int ln = (ent >> 17) & 127, j = ent & 0x1FFFF;
            const float4* F = fi4 + (size_t)j * 16 + qp * 8;
            const float4* G = fp4 + (size_t)j * 8 + qp * 4;
            float aI = 0.f, aP = 0.f;
            #pragma unroll
            for (int t = 0; t < 8; ++t) aI += DOT4(F[t], wi[t]);
            #pragma unroll
            for (int t = 0; t < 4; ++t) aP += DOT4(G[t], wp[t]);
            aI += __shfl_xor(aI, 16);
            aP += __shfl_xor(aP, 16);
            if (val) atomicAdd(&s_acc[ln][qp * 16 + o], qp ? aP : aI);
        }
    }
    __syncthreads();

    {   // BN + ReLU -> cat
        const int c = tid & 31;
        float g, b, m, v;
        if (c < 16) { g = gi[c]; b = bi[c]; m = mi[c]; v = vi[c]; }
        else        { g = gp[c - 16]; b = bp[c - 16]; m = mp[c - 16]; v = vp[c - 16]; }
        float sc = g * rsqrtf(v + EPSF);
        float* cat = ws + CAT;
        const int grp = tid >> 5;
        for (int r = 0; r < 16; ++r) {
            int ln = r * 8 + grp;
            if (ln < vcount)
                cat[(size_t)(gbase + ln) * 32 + c] =
                    fmaxf((s_acc[ln][c] - m) * sc + b, 0.f);
        }
    }
}

// vis conv on cat (reuses saved sorted lists) + BN/ReLU + sigmoid + blend
__global__ __launch_bounds__(256, 3) void convB(
    float* __restrict__ ws,
    const float* __restrict__ gv, const float* __restrict__ bv,
    const float* __restrict__ mv, const float* __restrict__ vv,
    const float* __restrict__ w2, float* __restrict__ out)
{
    __shared__ int s_koff[128];
    __shared__ int s_list[CAP2];
    __shared__ float s_acc[TVOX][16];
    __shared__ int s_next;

    const int tid = threadIdx.x;
    const int lane = tid & 63, wv = tid >> 6;
    const int l32 = lane & 31, qp = (lane >> 4) & 1, o = lane & 15, s2 = lane >> 5;
    const int blk = blockIdx.x, gbase = blk * TVOX;
    const int vcount = min(TVOX, N_VOX - gbase);

    if (tid == 0) s_next = 0;
    const int* kfo = (const int*)(ws + KOFF) + (size_t)blk * 128;
    if (tid < K3) s_koff[tid] = kfo[tid];
    __syncthreads();
    const int tot = s_koff[K3 - 1];
    const int* slo = (const int*)(ws + SLIST) + (size_t)blk * CAP2;
    for (int p = tid; p < tot; p += 256) s_list[p] = slo[p];

    const float4* __restrict__ c4 = (const float4*)(ws + CAT);

    // center tap: init s_acc
    {
        float4 wvr[4];
        const float4* WV = (const float4*)(ws + WVT + CENTER_K * 512);
        #pragma unroll
        for (int t = 0; t < 4; ++t) wvr[t] = WV[t * 32 + l32];
        for (int i = 0; i < 16; ++i) {
            int ln = wv * 32 + i * 2 + s2;
            bool val = ln < vcount;
            int j = gbase + (val ? ln : 0);
            const float4* F = c4 + (size_t)j * 8 + qp * 4;
            float aV = 0.f;
            #pragma unroll
            for (int t = 0; t < 4; ++t) aV += DOT4(F[t], wvr[t]);
            aV += __shfl_xor(aV, 16);
            if (val && qp == 0) s_acc[ln][o] = aV;
        }
    }
    __syncthreads();   // also covers s_list load

    while (true) {
        int sseg;
        if (lane == 0) sseg = atomicAdd(&s_next, 1);
        sseg = __shfl(sseg, 0);
        if (sseg >= K3) break;
        int pbeg = sseg ? s_koff[sseg - 1] : 0;
        int pend = s_koff[sseg];
        if (pbeg >= pend) continue;
        float4 wvr[4];
        const float4* WV = (const float4*)(ws + WVT + sseg * 512);
        #pragma unroll
        for (int t = 0; t < 4; ++t) wvr[t] = WV[t * 32 + l32];
        for (int p = pbeg; p < pend; p += 2) {
            int pp = p + s2;
            bool val = pp < pend;
            int ent = s_list[val ? pp : p];
            int ln = (ent >> 17) & 127, j = ent & 0x1FFFF;
            const float4* F = c4 + (size_t)j * 8 + qp * 4;
            float aV = 0.f;
            #pragma unroll
            for (int t = 0; t < 4; ++t) aV += DOT4(F[t], wvr[t]);
            aV += __shfl_xor(aV, 16);
            if (val && qp == 0) atomicAdd(&s_acc[ln][o], aV);
        }
    }
    __syncthreads();

    {   // BN + ReLU + sigmoid gate + blend -> out
        float sV = gv[o] * rsqrtf(vv[o] + EPSF);
        float bV = bv[o], mV = mv[o], w2_ = w2[o];
        const float* cat = ws + CAT;
        const int grp = tid >> 4;
        for (int r = 0; r < 8; ++r) {
            int ln = r * 16 + grp;
            float h = 0.f, xi = 0.f, xp = 0.f;
            if (ln < vcount) {
                int n = gbase + ln;
                h = fmaxf((s_acc[ln][o] - mV) * sV + bV, 0.f);
                xi = cat[(size_t)n * 32 + o];
                xp = cat[(size_t)n * 32 + 16 + o];
            }
            float ph = h * w2_;
            ph += __shfl_xor(ph, 1); ph += __shfl_xor(ph, 2);
            ph += __shfl_xor(ph, 4); ph += __shfl_xor(ph, 8);
            if (ln < vcount) {
                float vis = 1.f / (1.f + expf(-ph));
                out[(size_t)(gbase + ln) * 16 + o] = vis * xi + (1.f - vis) * xp;
            }
        }
    }
}

extern "C" void kernel_launch(void* const* d_in, const int* in_sizes, int n_in,
                              void* d_out, int out_size, void* d_ws, size_t ws_size,
                              hipStream_t stream) {
    const float* fimg = (const float*)d_in[0];
    const float* fpts = (const float*)d_in[1];
    const int*   nbr  = (const int*)d_in[2];
    const float* Wimg = (const float*)d_in[3];
    const float* gi = (const float*)d_in[4];
    const float* bi = (const float*)d_in[5];
    const float* mi = (const float*)d_in[6];
    const float* vi = (const float*)d_in[7];
    const float* Wpts = (const float*)d_in[8];
    const float* gp = (const float*)d_in[9];
    const float* bp = (const float*)d_in[10];
    const float* mp = (const float*)d_in[11];
    const float* vp = (const float*)d_in[12];
    const float* Wvis = (const float*)d_in[13];
    const float* gv = (const float*)d_in[14];
    const float* bv = (const float*)d_in[15];
    const float* mv = (const float*)d_in[16];
    const float* vv = (const float*)d_in[17];
    const float* w2 = (const float*)d_in[18];
    float* out = (float*)d_out;
    float* ws = (float*)d_ws;

    hipMemsetAsync(ws + GCNT, 0, 1024 * sizeof(int), stream);
    hipLaunchKernelGGL(prep_transpose, dim3(500), dim3(256), 0, stream,
                       Wimg, Wpts, Wvis, ws);
    hipLaunchKernelGGL(build, dim3(4096), dim3(256), 0, stream, nbr, ws);
    hipLaunchKernelGGL(convA, dim3(NBLK), dim3(256), 0, stream,
                       fimg, fpts, ws, gi, bi, mi, vi, gp, bp, mp, vp);
    hipLaunchKernelGGL(convB, dim3(NBLK), dim3(256), 0, stream,
                       ws, gv, bv, mv, vv, w2, out);
}

// Round 10
// 300.575 us; speedup vs baseline: 2.0039x; 2.0039x over previous
//
#include <hip/hip_runtime.h>
#include <hip/hip_bf16.h>

#define N_VOX 100000
#define K3 125
#define CENTER_K 62
#define NTILE 782
#define KSEG 2700
#define EPSF 1e-5f

// ws float-word offsets
#define KC    0            // kcur[125*16] (2000, pad 2048)
#define TCNT  2048         // per-tile entry totals [1024]
#define TOFF  3072         // exclusive tile offsets [1024]
#define VOFFP 4096         // packed per-voxel (ex<<6 | cnt) [100000] -> 104096
#define KL    104096       // int2 [125][KSEG] = 675,000 words -> 779096
#define SCR   779096       // uint per (entry): [entry][16] (bf16 aP<<16|aI) 310K entries -> 5,739,096
#define SCRV  779096       // overlay (B-phase): bf16 [entry][16]
#define CAT   5739096      // f32 [N][32] -> end 8,939,096 words = 35.8 MB

// ---- build: per-tile ballot-rank compaction; writes k-bucketed work list ----
__global__ __launch_bounds__(512) void build(const int* __restrict__ nbr,
                                             float* __restrict__ ws)
{
    __shared__ unsigned long long s_m0[128], s_m1[128];
    __shared__ int s_cnt[128], s_off[128];

    const int tid = threadIdx.x, lane = tid & 63, wv = tid >> 6;
    const int t = blockIdx.x, gbase = t * 128;
    const int vcount = min(128, N_VOX - gbase);

    if (tid < 128) s_cnt[tid] = 0;
    __syncthreads();

    for (int i = 0; i < 16; ++i) {
        int ln = wv * 16 + i;
        if (ln >= vcount) continue;          // wave-uniform
        const int* row = nbr + (size_t)(gbase + ln) * K3;
        int v0 = row[lane];
        bool ok0 = (v0 < N_VOX) && (lane != CENTER_K);
        unsigned long long m0 = __ballot(ok0);
        int v1 = (lane < 61) ? row[64 + lane] : N_VOX;
        bool ok1 = (lane < 61) && (v1 < N_VOX);
        unsigned long long m1 = __ballot(ok1);
        if (lane == 0) {
            s_m0[ln] = m0; s_m1[ln] = m1;
            s_cnt[ln] = __popcll(m0) + __popcll(m1);
        }
    }
    __syncthreads();

    if (tid < 128) s_off[tid] = s_cnt[tid];
    __syncthreads();
    for (int d = 1; d < 128; d <<= 1) {
        int v = 0;
        if (tid < 128 && tid >= d) v = s_off[tid - d];
        __syncthreads();
        if (tid < 128) s_off[tid] += v;
        __syncthreads();
    }
    if (tid == 0) ((int*)(ws + TCNT))[t] = s_off[127];
    __syncthreads();

    int* kcur = (int*)(ws + KC);
    int2* klist = (int2*)(ws + KL);
    int* voffp = (int*)(ws + VOFFP);

    for (int i = 0; i < 16; ++i) {
        int ln = wv * 16 + i;
        if (ln >= vcount) continue;
        int ex = s_off[ln] - s_cnt[ln];
        if (lane == 0) voffp[gbase + ln] = (ex << 6) | min(s_cnt[ln], 63);
        const int* row = nbr + (size_t)(gbase + ln) * K3;
        unsigned long long m0 = s_m0[ln], m1 = s_m1[ln];
        unsigned long long below = (lane == 63) ? 0xFFFFFFFFFFFFFFFFull >> 1
                                                : ((1ull << lane) - 1);
        if ((m0 >> lane) & 1) {
            int j = row[lane];
            int local = ex + __popcll(m0 & below);
            int kp = atomicAdd(&kcur[lane * 16], 1);
            if (kp < KSEG) klist[lane * KSEG + kp] = make_int2((t << 10) | local, j);
        }
        if (lane < 61 && ((m1 >> lane) & 1)) {
            int j = row[64 + lane];
            int local = ex + __popcll(m0) + __popcll(m1 & below);
            int kp = atomicAdd(&kcur[(64 + lane) * 16], 1);
            if (kp < KSEG) klist[(64 + lane) * KSEG + kp] = make_int2((t << 10) | local, j);
        }
    }
}

// ---- scan782: exclusive scan of per-tile totals (one block) ----
__global__ __launch_bounds__(1024) void scan782(float* __restrict__ ws)
{
    __shared__ int s[1024];
    const int tid = threadIdx.x;
    const int* tcnt = (const int*)(ws + TCNT);
    int own = (tid < NTILE) ? tcnt[tid] : 0;
    s[tid] = own;
    __syncthreads();
    for (int d = 1; d < 1024; d <<= 1) {
        int v = 0;
        if (tid >= d) v = s[tid - d];
        __syncthreads();
        s[tid] += v;
        __syncthreads();
    }
    ((int*)(ws + TOFF))[tid] = s[tid] - own;
}

// ---- A1: img+pts pair compute. thread-per-(pair,o); W cols in VGPRs; bf16 store ----
__global__ __launch_bounds__(256) void convA1(
    const float* __restrict__ fimg, const float* __restrict__ fpts,
    const float* __restrict__ Wimg, const float* __restrict__ Wpts,
    float* __restrict__ ws)
{
    const int k = blockIdx.x;
    const int o = threadIdx.x & 15, grp = threadIdx.x >> 4;
    float Wi[64];
    #pragma unroll
    for (int c = 0; c < 64; ++c) Wi[c] = Wimg[k * 1024 + c * 16 + o];
    float Wp[32];
    #pragma unroll
    for (int c = 0; c < 32; ++c) Wp[c] = Wpts[k * 512 + c * 16 + o];

    int cnt = min(((const int*)(ws + KC))[k * 16], KSEG);
    const int2* __restrict__ kl = (const int2*)(ws + KL) + (size_t)k * KSEG;
    const int* __restrict__ toff = (const int*)(ws + TOFF);
    unsigned* __restrict__ scru = (unsigned*)(ws + SCR);
    const float4* __restrict__ fi4 = (const float4*)fimg;
    const float4* __restrict__ fp4 = (const float4*)fpts;

    for (int p = blockIdx.y * 16 + grp; p < cnt; p += gridDim.y * 16) {
        int2 e = kl[p];
        int gpos = toff[e.x >> 10] + (e.x & 1023);
        int j = e.y;
        const float4* fr = fi4 + (size_t)j * 16;
        const float4* gr = fp4 + (size_t)j * 8;
        float a0 = 0.f, a1 = 0.f, b0 = 0.f, b1 = 0.f;
        #pragma unroll
        for (int c4 = 0; c4 < 8; ++c4) {
            float4 f = fr[c4];
            a0 += f.x*Wi[4*c4] + f.y*Wi[4*c4+1] + f.z*Wi[4*c4+2] + f.w*Wi[4*c4+3];
            float4 g = fr[8 + c4];
            a1 += g.x*Wi[32+4*c4] + g.y*Wi[32+4*c4+1] + g.z*Wi[32+4*c4+2] + g.w*Wi[32+4*c4+3];
        }
        #pragma unroll
        for (int c4 = 0; c4 < 4; ++c4) {
            float4 f = gr[c4];
            b0 += f.x*Wp[4*c4] + f.y*Wp[4*c4+1] + f.z*Wp[4*c4+2] + f.w*Wp[4*c4+3];
            float4 g = gr[4 + c4];
            b1 += g.x*Wp[16+4*c4] + g.y*Wp[16+4*c4+1] + g.z*Wp[16+4*c4+2] + g.w*Wp[16+4*c4+3];
        }
        unsigned lo = (unsigned)__builtin_bit_cast(unsigned short, __float2bfloat16(a0 + a1));
        unsigned hi = (unsigned)__builtin_bit_cast(unsigned short, __float2bfloat16(b0 + b1));
        scru[(size_t)gpos * 16 + o] = (hi << 16) | lo;
    }
}

// ---- A2: center tap + reduce scratch + BN/ReLU -> cat ----
__global__ __launch_bounds__(256) void convA2(
    const float* __restrict__ fimg, const float* __restrict__ fpts,
    const float* __restrict__ Wimg, const float* __restrict__ Wpts,
    float* __restrict__ ws,
    const float* __restrict__ gi, const float* __restrict__ bi,
    const float* __restrict__ mi, const float* __restrict__ vi,
    const float* __restrict__ gp, const float* __restrict__ bp,
    const float* __restrict__ mp, const float* __restrict__ vp)
{
    const int o = threadIdx.x & 15, slot = threadIdx.x >> 4;
    float Wi[64];
    #pragma unroll
    for (int c = 0; c < 64; ++c) Wi[c] = Wimg[CENTER_K * 1024 + c * 16 + o];
    float Wp[32];
    #pragma unroll
    for (int c = 0; c < 32; ++c) Wp[c] = Wpts[CENTER_K * 512 + c * 16 + o];
    float sI = gi[o] * rsqrtf(vi[o] + EPSF), bI = bi[o], mI = mi[o];
    float sP = gp[o] * rsqrtf(vp[o] + EPSF), bP = bp[o], mP = mp[o];

    const float4* __restrict__ fi4 = (const float4*)fimg;
    const float4* __restrict__ fp4 = (const float4*)fpts;
    const int* __restrict__ voffp = (const int*)(ws + VOFFP);
    const int* __restrict__ toff = (const int*)(ws + TOFF);
    const unsigned* __restrict__ scru = (const unsigned*)(ws + SCR);
    float* __restrict__ cat = ws + CAT;

    for (int n = blockIdx.x * 16 + slot; n < N_VOX; n += gridDim.x * 16) {
        const float4* fr = fi4 + (size_t)n * 16;
        const float4* gr = fp4 + (size_t)n * 8;
        float a0 = 0.f, a1 = 0.f, b0 = 0.f, b1 = 0.f;
        #pragma unroll
        for (int c4 = 0; c4 < 8; ++c4) {
            float4 f = fr[c4];
            a0 += f.x*Wi[4*c4] + f.y*Wi[4*c4+1] + f.z*Wi[4*c4+2] + f.w*Wi[4*c4+3];
            float4 g = fr[8 + c4];
            a1 += g.x*Wi[32+4*c4] + g.y*Wi[32+4*c4+1] + g.z*Wi[32+4*c4+2] + g.w*Wi[32+4*c4+3];
        }
        #pragma unroll
        for (int c4 = 0; c4 < 4; ++c4) {
            float4 f = gr[c4];
            b0 += f.x*Wp[4*c4] + f.y*Wp[4*c4+1] + f.z*Wp[4*c4+2] + f.w*Wp[4*c4+3];
            float4 g = gr[4 + c4];
            b1 += g.x*Wp[16+4*c4] + g.y*Wp[16+4*c4+1] + g.z*Wp[16+4*c4+2] + g.w*Wp[16+4*c4+3];
        }
        float aI = a0 + a1, aP = b0 + b1;
        int pk = voffp[n];
        int gpos0 = toff[n >> 7] + (pk >> 6);
        int cnt = pk & 63;
        for (int r = 0; r < cnt; ++r) {
            unsigned u = scru[(size_t)(gpos0 + r) * 16 + o];
            aI += __bfloat162float(__builtin_bit_cast(__hip_bfloat16, (unsigned short)(u & 0xffff)));
            aP += __bfloat162float(__builtin_bit_cast(__hip_bfloat16, (unsigned short)(u >> 16)));
        }
        cat[(size_t)n * 32 + o]      = fmaxf((aI - mI) * sI + bI, 0.f);
        cat[(size_t)n * 32 + 16 + o] = fmaxf((aP - mP) * sP + bP, 0.f);
    }
}

// ---- B1: vis pair compute on cat; bf16 store ----
__global__ __launch_bounds__(256) void convB1(
    const float* __restrict__ Wvis, float* __restrict__ ws)
{
    const int k = blockIdx.x;
    const int o = threadIdx.x & 15, grp = threadIdx.x >> 4;
    float Wv[32];
    #pragma unroll
    for (int c = 0; c < 32; ++c) Wv[c] = Wvis[k * 512 + c * 16 + o];

    int cnt = min(((const int*)(ws + KC))[k * 16], KSEG);
    const int2* __restrict__ kl = (const int2*)(ws + KL) + (size_t)k * KSEG;
    const int* __restrict__ toff = (const int*)(ws + TOFF);
    __hip_bfloat16* __restrict__ scrv = (__hip_bfloat16*)(ws + SCRV);
    const float4* __restrict__ c4p = (const float4*)(ws + CAT);

    for (int p = blockIdx.y * 16 + grp; p < cnt; p += gridDim.y * 16) {
        int2 e = kl[p];
        int gpos = toff[e.x >> 10] + (e.x & 1023);
        const float4* cr = c4p + (size_t)e.y * 8;
        float a0 = 0.f, a1 = 0.f;
        #pragma unroll
        for (int c4 = 0; c4 < 4; ++c4) {
            float4 f = cr[c4];
            a0 += f.x*Wv[4*c4] + f.y*Wv[4*c4+1] + f.z*Wv[4*c4+2] + f.w*Wv[4*c4+3];
            float4 g = cr[4 + c4];
            a1 += g.x*Wv[16+4*c4] + g.y*Wv[16+4*c4+1] + g.z*Wv[16+4*c4+2] + g.w*Wv[16+4*c4+3];
        }
        scrv[(size_t)gpos * 16 + o] = __float2bfloat16(a0 + a1);
    }
}

// ---- B2: vis center + reduce + BN/ReLU + sigmoid + blend -> out ----
__global__ __launch_bounds__(256) void convB2(
    const float* __restrict__ Wvis, float* __restrict__ ws,
    const float* __restrict__ gv, const float* __restrict__ bv,
    const float* __restrict__ mv, const float* __restrict__ vv,
    const float* __restrict__ w2, float* __restrict__ out)
{
    const int o = threadIdx.x & 15, slot = threadIdx.x >> 4;
    float Wv[32];
    #pragma unroll
    for (int c = 0; c < 32; ++c) Wv[c] = Wvis[CENTER_K * 512 + c * 16 + o];
    float sV = gv[o] * rsqrtf(vv[o] + EPSF);
    float bV = bv[o], mV = mv[o], w2_ = w2[o];

    const int* __restrict__ voffp = (const int*)(ws + VOFFP);
    const int* __restrict__ toff = (const int*)(ws + TOFF);
    const __hip_bfloat16* __restrict__ scrv = (const __hip_bfloat16*)(ws + SCRV);
    const float4* __restrict__ c4p = (const float4*)(ws + CAT);
    const float* __restrict__ cat = ws + CAT;

    for (int n = blockIdx.x * 16 + slot; n < N_VOX; n += gridDim.x * 16) {
        const float4* cr = c4p + (size_t)n * 8;
        float a0 = 0.f, a1 = 0.f;
        #pragma unroll
        for (int c4 = 0; c4 < 4; ++c4) {
            float4 f = cr[c4];
            a0 += f.x*Wv[4*c4] + f.y*Wv[4*c4+1] + f.z*Wv[4*c4+2] + f.w*Wv[4*c4+3];
            float4 g = cr[4 + c4];
            a1 += g.x*Wv[16+4*c4] + g.y*Wv[16+4*c4+1] + g.z*Wv[16+4*c4+2] + g.w*Wv[16+4*c4+3];
        }
        float aV = a0 + a1;
        int pk = voffp[n];
        int gpos0 = toff[n >> 7] + (pk >> 6);
        int cnt = pk & 63;
        for (int r = 0; r < cnt; ++r)
            aV += __bfloat162float(scrv[(size_t)(gpos0 + r) * 16 + o]);
        float h = fmaxf((aV - mV) * sV + bV, 0.f);
        float ph = h * w2_;
        ph += __shfl_xor(ph, 1); ph += __shfl_xor(ph, 2);
        ph += __shfl_xor(ph, 4); ph += __shfl_xor(ph, 8);
        float vis = 1.f / (1.f + expf(-ph));
        float xi = cat[(size_t)n * 32 + o];
        float xp = cat[(size_t)n * 32 + 16 + o];
        out[(size_t)n * 16 + o] = vis * xi + (1.f - vis) * xp;
    }
}

extern "C" void kernel_launch(void* const* d_in, const int* in_sizes, int n_in,
                              void* d_out, int out_size, void* d_ws, size_t ws_size,
                              hipStream_t stream) {
    const float* fimg = (const float*)d_in[0];
    const float* fpts = (const float*)d_in[1];
    const int*   nbr  = (const int*)d_in[2];
    const float* Wimg = (const float*)d_in[3];
    const float* gi = (const float*)d_in[4];
    const float* bi = (const float*)d_in[5];
    const float* mi = (const float*)d_in[6];
    const float* vi = (const float*)d_in[7];
    const float* Wpts = (const float*)d_in[8];
    const float* gp = (const float*)d_in[9];
    const float* bp = (const float*)d_in[10];
    const float* mp = (const float*)d_in[11];
    const float* vp = (const float*)d_in[12];
    const float* Wvis = (const float*)d_in[13];
    const float* gv = (const float*)d_in[14];
    const float* bv = (const float*)d_in[15];
    const float* mv = (const float*)d_in[16];
    const float* vv = (const float*)d_in[17];
    const float* w2 = (const float*)d_in[18];
    float* out = (float*)d_out;
    float* ws = (float*)d_ws;

    hipMemsetAsync(ws + KC, 0, 2000 * sizeof(int), stream);
    hipLaunchKernelGGL(build, dim3(NTILE), dim3(512), 0, stream, nbr, ws);
    hipLaunchKernelGGL(scan782, dim3(1), dim3(1024), 0, stream, ws);
    hipLaunchKernelGGL(convA1, dim3(125, 24), dim3(256), 0, stream,
                       fimg, fpts, Wimg, Wpts, ws);
    hipLaunchKernelGGL(convA2, dim3(512), dim3(256), 0, stream,
                       fimg, fpts, Wimg, Wpts, ws, gi, bi, mi, vi, gp, bp, mp, vp);
    hipLaunchKernelGGL(convB1, dim3(125, 24), dim3(256), 0, stream, Wvis, ws);
    hipLaunchKernelGGL(convB2, dim3(512), dim3(256), 0, stream,
                       Wvis, ws, gv, bv, mv, vv, w2, out);
}

// Round 11
// 243.319 us; speedup vs baseline: 2.4755x; 1.2353x over previous
//
#include <hip/hip_runtime.h>

#define N_VOX 100000
#define K3 125
#define CENTER_K 62
#define GV 256
#define NGRP 391            // ceil(100000/256); last group has 160 voxels
#define CAPG 1152           // per-group entry cap (mean ~775, sd ~28)
#define EPSF 1e-5f

// ws float-word offsets
#define WIT 0               // W_img lane-order [125][8][32][4]  (c = qq*32+t*4+e, l32 = qq*16+o)
#define WPT 128000          // W_pts lane-order [125][4][32][4]  (c = qq*16+t*4+e)
#define WVT 192000          // W_vis lane-order [125][4][32][4]
#define GKOF 256000         // per-group inclusive k-offsets [NGRP][128]
#define GLST 306048         // per-group k-sorted entries [NGRP][CAPG]  (ln<<17 | j)
#define CAT  756480         // f32 [N_VOX][32]
// end = 3,956,480 words = 15.8 MB

#define DOT4(f_, g_) ((f_).x*(g_).x + (f_).y*(g_).y + (f_).z*(g_).z + (f_).w*(g_).w)

// lane-order W transpose (mapping verified in round-9 run)
__global__ __launch_bounds__(256) void prep_transpose(
    const float* __restrict__ Wi, const float* __restrict__ Wp,
    const float* __restrict__ Wv, float* __restrict__ ws)
{
    int i = blockIdx.x * 256 + threadIdx.x;
    if (i < 125 * 64 * 16) {            // img: i = k*1024 + c*16 + o
        int k = i >> 10, r = i & 1023;
        int c = r >> 4, oo = r & 15;
        int qq = c >> 5, t = (c >> 2) & 7, e = c & 3;
        ws[WIT + k * 1024 + t * 128 + (qq * 16 + oo) * 4 + e] = Wi[i];
    }
    if (i < 125 * 32 * 16) {            // pts/vis: i = k*512 + c*16 + o
        int k = i >> 9, r = i & 511;
        int c = r >> 4, oo = r & 15;
        int qq = c >> 4, t = (c >> 2) & 3, e = c & 3;
        ws[WPT + k * 512 + t * 128 + (qq * 16 + oo) * 4 + e] = Wp[i];
        ws[WVT + k * 512 + t * 128 + (qq * 16 + oo) * 4 + e] = Wv[i];
    }
}

// one nbr pass -> per-group k-sorted lists via ballot masks + LDS count/scan/place
__global__ __launch_bounds__(512) void build(const int* __restrict__ nbr,
                                             float* __restrict__ ws)
{
    __shared__ unsigned long long s_m0[GV], s_m1[GV];
    __shared__ int s_kcnt[128], s_koff[128];

    const int tid = threadIdx.x, lane = tid & 63, wv = tid >> 6;
    const int g = blockIdx.x, gbase = g * GV;
    const int vcount = min(GV, N_VOX - gbase);

    if (tid < 128) s_kcnt[tid] = 0;
    __syncthreads();

    for (int i = 0; i < 32; ++i) {
        int ln = wv * 32 + i;
        if (ln >= vcount) break;                 // wave-uniform
        const int* row = nbr + (size_t)(gbase + ln) * K3;
        int v0 = row[lane];
        bool ok0 = (v0 < N_VOX) && (lane != CENTER_K);
        unsigned long long m0 = __ballot(ok0);
        bool ok1 = false;
        if (lane < 61) ok1 = (row[64 + lane] < N_VOX);
        unsigned long long m1 = __ballot(ok1);
        if (lane == 0) { s_m0[ln] = m0; s_m1[ln] = m1; }
        if (ok0) atomicAdd(&s_kcnt[lane], 1);
        if (ok1) atomicAdd(&s_kcnt[64 + lane], 1);
    }
    __syncthreads();

    if (tid < 128) s_koff[tid] = (tid < K3) ? s_kcnt[tid] : 0;
    __syncthreads();
    for (int d = 1; d < 128; d <<= 1) {          // inclusive scan
        int v = 0;
        if (tid < 128 && tid >= d) v = s_koff[tid - d];
        __syncthreads();
        if (tid < 128) s_koff[tid] += v;
        __syncthreads();
    }
    if (tid < 128) s_kcnt[tid] = tid ? s_koff[tid - 1] : 0;   // cursors
    __syncthreads();

    int* glist = (int*)(ws + GLST) + (size_t)g * CAPG;
    for (int i = 0; i < 32; ++i) {
        int ln = wv * 32 + i;
        if (ln >= vcount) break;
        unsigned long long m0 = s_m0[ln], m1 = s_m1[ln];
        const int* row = nbr + (size_t)(gbase + ln) * K3;   // L2-warm re-read
        if ((m0 >> lane) & 1) {
            int j = row[lane];
            int pos = atomicAdd(&s_kcnt[lane], 1);
            if (pos < CAPG) glist[pos] = (ln << 17) | j;
        }
        if (lane < 61 && ((m1 >> lane) & 1)) {
            int j = row[64 + lane];
            int pos = atomicAdd(&s_kcnt[64 + lane], 1);
            if (pos < CAPG) glist[pos] = (ln << 17) | j;
        }
    }
    __syncthreads();
    if (tid < K3)
        ((int*)(ws + GKOF))[(size_t)g * 128 + tid] = min(s_koff[tid], CAPG);
}

// img+pts conv: center init + k-march with LDS accumulation (shapes proven round-9)
__global__ __launch_bounds__(512, 4) void convA(
    const float* __restrict__ fimg, const float* __restrict__ fpts,
    float* __restrict__ ws,
    const float* __restrict__ gi, const float* __restrict__ bi,
    const float* __restrict__ mi, const float* __restrict__ vi,
    const float* __restrict__ gp, const float* __restrict__ bp,
    const float* __restrict__ mp, const float* __restrict__ vp)
{
    __shared__ int s_koff[128];
    __shared__ int s_list[CAPG];
    __shared__ float s_acc[GV][32];
    __shared__ int s_next;

    const int tid = threadIdx.x;
    const int lane = tid & 63, wv = tid >> 6;
    const int l32 = lane & 31, qp = (lane >> 4) & 1, o = lane & 15, s2 = lane >> 5;
    const int g = blockIdx.x, gbase = g * GV;
    const int vcount = min(GV, N_VOX - gbase);

    if (tid == 0) s_next = 0;
    if (tid < K3) s_koff[tid] = ((const int*)(ws + GKOF))[(size_t)g * 128 + tid];
    __syncthreads();
    const int tot = s_koff[K3 - 1];
    const int* glist = (const int*)(ws + GLST) + (size_t)g * CAPG;
    for (int p = tid; p < tot; p += 512) s_list[p] = glist[p];

    const float4* __restrict__ fi4 = (const float4*)fimg;
    const float4* __restrict__ fp4 = (const float4*)fpts;

    // center tap: init s_acc (2 voxels per wave-iter via s2 halves)
    {
        float4 wi[8], wp[4];
        const float4* WI = (const float4*)(ws + WIT + CENTER_K * 1024);
        const float4* WP = (const float4*)(ws + WPT + CENTER_K * 512);
        #pragma unroll
        for (int t = 0; t < 8; ++t) wi[t] = WI[t * 32 + l32];
        #pragma unroll
        for (int t = 0; t < 4; ++t) wp[t] = WP[t * 32 + l32];
        for (int i = 0; i < 16; ++i) {
            int ln = wv * 32 + i * 2 + s2;
            bool val = ln < vcount;
            int j = gbase + (val ? ln : 0);
            const float4* F = fi4 + (size_t)j * 16 + qp * 8;
            const float4* G = fp4 + (size_t)j * 8 + qp * 4;
            float aI = 0.f, aP = 0.f;
            #pragma unroll
            for (int t = 0; t < 8; ++t) aI += DOT4(F[t], wi[t]);
            #pragma unroll
            for (int t = 0; t < 4; ++t) aP += DOT4(G[t], wp[t]);
            aI += __shfl_xor(aI, 16);
            aP += __shfl_xor(aP, 16);
            if (val) s_acc[ln][qp * 16 + o] = qp ? aP : aI;
        }
    }
    __syncthreads();   // covers s_list load + center init

    // k-segment march: W[k] in regs, 2 pairs per wave-iter
    while (true) {
        int sseg;
        if (lane == 0) sseg = atomicAdd(&s_next, 1);
        sseg = __shfl(sseg, 0);
        if (sseg >= K3) break;
        int pbeg = sseg ? s_koff[sseg - 1] : 0;
        int pend = s_koff[sseg];
        if (pbeg >= pend) continue;
        float4 wi[8], wp[4];
        const float4* WI = (const float4*)(ws + WIT + sseg * 1024);
        const float4* WP = (const float4*)(ws + WPT + sseg * 512);
        #pragma unroll
        for (int t = 0; t < 8; ++t) wi[t] = WI[t * 32 + l32];
        #pragma unroll
        for (int t = 0; t < 4; ++t) wp[t] = WP[t * 32 + l32];
        for (int p = pbeg; p < pend; p += 2) {
            int pp = p + s2;
            bool val = pp < pend;
            int ent = s_list[val ? pp : p];
            int ln = (ent >> 17) & 255, j = ent & 0x1FFFF;
            const float4* F = fi4 + (size_t)j * 16 + qp * 8;
            const float4* G = fp4 + (size_t)j * 8 + qp * 4;
            float aI = 0.f, aP = 0.f;
            #pragma unroll
            for (int t = 0; t < 8; ++t) aI += DOT4(F[t], wi[t]);
            #pragma unroll
            for (int t = 0; t < 4; ++t) aP += DOT4(G[t], wp[t]);
            aI += __shfl_xor(aI, 16);
            aP += __shfl_xor(aP, 16);
            if (val) atomicAdd(&s_acc[ln][qp * 16 + o], qp ? aP : aI);
        }
    }
    __syncthreads();

    {   // BN + ReLU -> cat
        const int c = tid & 31;
        float gg, bb, mm, vv2;
        if (c < 16) { gg = gi[c]; bb = bi[c]; mm = mi[c]; vv2 = vi[c]; }
        else        { gg = gp[c - 16]; bb = bp[c - 16]; mm = mp[c - 16]; vv2 = vp[c - 16]; }
        float sc = gg * rsqrtf(vv2 + EPSF);
        float* cat = ws + CAT;
        const int grp = tid >> 5;
        for (int r = 0; r < 16; ++r) {
            int ln = r * 16 + grp;
            if (ln < vcount)
                cat[(size_t)(gbase + ln) * 32 + c] =
                    fmaxf((s_acc[ln][c] - mm) * sc + bb, 0.f);
        }
    }
}

// vis conv on cat + BN/ReLU + sigmoid + blend
__global__ __launch_bounds__(512, 4) void convB(
    float* __restrict__ ws,
    const float* __restrict__ gv, const float* __restrict__ bv,
    const float* __restrict__ mv, const float* __restrict__ vv,
    const float* __restrict__ w2, float* __restrict__ out)
{
    __shared__ int s_koff[128];
    __shared__ int s_list[CAPG];
    __shared__ float s_acc[GV][16];
    __shared__ int s_next;

    const int tid = threadIdx.x;
    const int lane = tid & 63, wv = tid >> 6;
    const int l32 = lane & 31, qp = (lane >> 4) & 1, o = lane & 15, s2 = lane >> 5;
    const int g = blockIdx.x, gbase = g * GV;
    const int vcount = min(GV, N_VOX - gbase);

    if (tid == 0) s_next = 0;
    if (tid < K3) s_koff[tid] = ((const int*)(ws + GKOF))[(size_t)g * 128 + tid];
    __syncthreads();
    const int tot = s_koff[K3 - 1];
    const int* glist = (const int*)(ws + GLST) + (size_t)g * CAPG;
    for (int p = tid; p < tot; p += 512) s_list[p] = glist[p];

    const float4* __restrict__ c4 = (const float4*)(ws + CAT);

    // center tap: init s_acc
    {
        float4 wvr[4];
        const float4* WV = (const float4*)(ws + WVT + CENTER_K * 512);
        #pragma unroll
        for (int t = 0; t < 4; ++t) wvr[t] = WV[t * 32 + l32];
        for (int i = 0; i < 16; ++i) {
            int ln = wv * 32 + i * 2 + s2;
            bool val = ln < vcount;
            int j = gbase + (val ? ln : 0);
            const float4* F = c4 + (size_t)j * 8 + qp * 4;
            float aV = 0.f;
            #pragma unroll
            for (int t = 0; t < 4; ++t) aV += DOT4(F[t], wvr[t]);
            aV += __shfl_xor(aV, 16);
            if (val && qp == 0) s_acc[ln][o] = aV;
        }
    }
    __syncthreads();

    while (true) {
        int sseg;
        if (lane == 0) sseg = atomicAdd(&s_next, 1);
        sseg = __shfl(sseg, 0);
        if (sseg >= K3) break;
        int pbeg = sseg ? s_koff[sseg - 1] : 0;
        int pend = s_koff[sseg];
        if (pbeg >= pend) continue;
        float4 wvr[4];
        const float4* WV = (const float4*)(ws + WVT + sseg * 512);
        #pragma unroll
        for (int t = 0; t < 4; ++t) wvr[t] = WV[t * 32 + l32];
        for (int p = pbeg; p < pend; p += 2) {
            int pp = p + s2;
            bool val = pp < pend;
            int ent = s_list[val ? pp : p];
            int ln = (ent >> 17) & 255, j = ent & 0x1FFFF;
            const float4* F = c4 + (size_t)j * 8 + qp * 4;
            float aV = 0.f;
            #pragma unroll
            for (int t = 0; t < 4; ++t) aV += DOT4(F[t], wvr[t]);
            aV += __shfl_xor(aV, 16);
            if (val && qp == 0) atomicAdd(&s_acc[ln][o], aV);
        }
    }
    __syncthreads();

    {   // BN + ReLU + sigmoid gate + blend -> out
        float sV = gv[o] * rsqrtf(vv[o] + EPSF);
        float bV = bv[o], mV = mv[o], w2_ = w2[o];
        const float* cat = ws + CAT;
        const int grp = tid >> 4;
        for (int r = 0; r < 8; ++r) {
            int ln = r * 32 + grp;
            float h = 0.f, xi = 0.f, xp = 0.f;
            if (ln < vcount) {
                int n = gbase + ln;
                h = fmaxf((s_acc[ln][o] - mV) * sV + bV, 0.f);
                xi = cat[(size_t)n * 32 + o];
                xp = cat[(size_t)n * 32 + 16 + o];
            }
            float ph = h * w2_;
            ph += __shfl_xor(ph, 1); ph += __shfl_xor(ph, 2);
            ph += __shfl_xor(ph, 4); ph += __shfl_xor(ph, 8);
            if (ln < vcount) {
                float vis = 1.f / (1.f + expf(-ph));
                out[(size_t)(gbase + ln) * 16 + o] = vis * xi + (1.f - vis) * xp;
            }
        }
    }
}

extern "C" void kernel_launch(void* const* d_in, const int* in_sizes, int n_in,
                              void* d_out, int out_size, void* d_ws, size_t ws_size,
                              hipStream_t stream) {
    const float* fimg = (const float*)d_in[0];
    const float* fpts = (const float*)d_in[1];
    const int*   nbr  = (const int*)d_in[2];
    const float* Wimg = (const float*)d_in[3];
    const float* gi = (const float*)d_in[4];
    const float* bi = (const float*)d_in[5];
    const float* mi = (const float*)d_in[6];
    const float* vi = (const float*)d_in[7];
    const float* Wpts = (const float*)d_in[8];
    const float* gp = (const float*)d_in[9];
    const float* bp = (const float*)d_in[10];
    const float* mp = (const float*)d_in[11];
    const float* vp = (const float*)d_in[12];
    const float* Wvis = (const float*)d_in[13];
    const float* gv = (const float*)d_in[14];
    const float* bv = (const float*)d_in[15];
    const float* mv = (const float*)d_in[16];
    const float* vv = (const float*)d_in[17];
    const float* w2 = (const float*)d_in[18];
    float* out = (float*)d_out;
    float* ws = (float*)d_ws;

    hipLaunchKernelGGL(prep_transpose, dim3(500), dim3(256), 0, stream,
                       Wimg, Wpts, Wvis, ws);
    hipLaunchKernelGGL(build, dim3(NGRP), dim3(512), 0, stream, nbr, ws);
    hipLaunchKernelGGL(convA, dim3(NGRP), dim3(512), 0, stream,
                       fimg, fpts, ws, gi, bi, mi, vi, gp, bp, mp, vp);
    hipLaunchKernelGGL(convB, dim3(NGRP), dim3(512), 0, stream,
                       ws, gv, bv, mv, vv, w2, out);
}